// Round 5
// baseline (300.526 us; speedup 1.0000x reference)
//
#include <hip/hip_runtime.h>
#include <math.h>

// ---------------- workspace layout (float offsets) ----------------
#define WS_E0   0       // E_s[19]
#define WS_E1   19      // E_t[19]
#define WS_G0   64      // G_s[361] (i<=j)
#define WS_G1   448     // G_t[361]
#define WS_Z    1152    // row sumexp [304]
#define WS_WBF  2048    // conv_w as bf16 [768*128] -> 49152 float slots
#define WS_PIX  51200   // per-pixel partials [34304][4], atomically accumulated
// total: 51200 + 137216 = 188416 floats = 754 KB

typedef __bf16 bf16x8 __attribute__((ext_vector_type(8)));
typedef float  f32x4  __attribute__((ext_vector_type(4)));

typedef const __attribute__((address_space(1))) unsigned int guint;
typedef       __attribute__((address_space(3))) unsigned int luint;

// ---------------- init: zero partials/accumulators + convert W to bf16 ----------------
// grid 536 x 256 (536*256 = 137216 = exactly the partial buffer)
__global__ void k_init(const float* __restrict__ conv_w, float* __restrict__ ws,
                       float* __restrict__ out) {
    const int bx = blockIdx.x, tid = threadIdx.x;
    ws[WS_PIX + bx * 256 + tid] = 0.f;
    if (bx < 96) {
        __bf16* Wb = (__bf16*)(ws + WS_WBF);
        #pragma unroll
        for (int j = 0; j < 4; j++) {
            int idx = bx * 1024 + j * 256 + tid;   // 96*1024 = 98304 = 768*128
            Wb[idx] = (__bf16)conv_w[idx];
        }
    }
    if (bx == 96) {
        for (int k = tid; k < 2048; k += 256) ws[k] = 0.f;
        if (tid < 2) out[tid] = 0.f;
    }
}

// ---------------- bilinear sample of t_logit row (65x65 -> 129x129) ----------------
__device__ __forceinline__ float t_resized(const float* __restrict__ Trow, int k) {
    int y = k / 129, x = k - y * 129;
    int y0 = y >> 1, x0 = x >> 1;
    int y1 = y0 + (y & 1), x1 = x0 + (x & 1);
    float fy = 0.5f * (float)(y & 1), fx = 0.5f * (float)(x & 1);
    float v00 = Trow[y0 * 65 + x0], v01 = Trow[y0 * 65 + x1];
    float v10 = Trow[y1 * 65 + x0], v11 = Trow[y1 * 65 + x1];
    float r0 = v00 + fx * (v01 - v00);
    float r1 = v10 + fx * (v11 - v10);
    return r0 + fy * (r1 - r0);
}

// ---------------- fused main: pi partials (0..2143) + rowstats (2144..2447) ----------
// pi role: (b,tile) x quarter (3 chunks of 64 ch). Per block:
//   resize -> xs (LDS) -> B-frags (regs) -> preload all A-frags+bias (regs)
//   -> 48 async global_load_lds row-copies of t_out into per-wave LDS tiles
//   -> single s_waitcnt vmcnt(0) -> 3 chunks of MFMA+exp epilogue, ZERO stalls
//   -> merge 16 partitions -> atomicAdd per-pixel partials.
// t-tile rows padded to 272 B: epilogue reads land 2 lanes/bank (free, m136).
__launch_bounds__(256, 2)
__global__ void k_main(const float* __restrict__ s_out, const float* __restrict__ t_out,
                       const float* __restrict__ bias,
                       const float* __restrict__ s_logit, const float* __restrict__ t_logit,
                       float* __restrict__ ws, float* __restrict__ out) {
    __shared__ __align__(16) char lds[69632];   // 17408 xs/scr + 4 waves * 13056 t-tiles
    const int tid = threadIdx.x;
    const int bx  = blockIdx.x;

    if (bx < 2144) {
        __bf16* xs  = (__bf16*)lds;     // 64px x 136c bf16
        float*  scr = (float*)lds;      // merge scratch (reuse)

        const int half = bx & 3;
        const int bt   = bx >> 2;
        const int b    = bt / 67;
        const int tile = bt - b * 67;
        const int hw0  = tile * 64;
        const bool tail = (tile == 66);

        // ---- bilinear resize 33x33 -> 65x65 tile into xs[px][c] ----
        {
            const float* Sb = s_out + b * 128 * 1089;
            #pragma unroll
            for (int ii = 0; ii < 32; ii++) {
                int idx = tid + ii * 256;
                int c = idx >> 6, px = idx & 63;
                int hw = hw0 + px;
                float v = 0.f;
                if (hw < 4225) {
                    int h = hw / 65, w = hw - h * 65;
                    int y0 = h >> 1, x0 = w >> 1;
                    int y1 = y0 + (h & 1), x1 = x0 + (w & 1);
                    float wy = 0.5f * (float)(h & 1), wx = 0.5f * (float)(w & 1);
                    const float* Sc = Sb + c * 1089;
                    float v00 = Sc[y0 * 33 + x0], v01 = Sc[y0 * 33 + x1];
                    float v10 = Sc[y1 * 33 + x0], v11 = Sc[y1 * 33 + x1];
                    float r0 = v00 + wx * (v01 - v00);
                    float r1 = v10 + wx * (v11 - v10);
                    v = r0 + wy * (r1 - r0);
                }
                xs[px * 136 + c] = (__bf16)v;
            }
        }
        __syncthreads();

        const int l = tid & 63, wv = tid >> 6, q = l >> 4, n = l & 15;

        // ---- B fragments (once) ----
        bf16x8 bfrag[4][4];
        #pragma unroll
        for (int pt = 0; pt < 4; pt++)
            #pragma unroll
            for (int kf = 0; kf < 4; kf++)
                bfrag[pt][kf] = *(const bf16x8*)&xs[(pt * 16 + n) * 136 + kf * 32 + q * 8];
        __syncthreads();   // xs dead; scr reused at merge

        // ---- preload ALL A-frags + bias for this block's 3 chunks ----
        const __bf16* Wbf = (const __bf16*)(ws + WS_WBF);
        bf16x8 afr[3][4];
        f32x4  bq[3];
        #pragma unroll
        for (int c = 0; c < 3; c++) {
            const int ob = (half * 3 + c) * 64 + wv * 16;
            const __bf16* Wr = Wbf + (size_t)(ob + n) * 128 + q * 8;
            #pragma unroll
            for (int kf = 0; kf < 4; kf++) afr[c][kf] = *(const bf16x8*)(Wr + kf * 32);
            bq[c] = *(const f32x4*)&bias[ob + q * 4];
        }

        // ---- async t_out fill: 48 row-copies into per-wave LDS tiles ----
        char* tw = lds + 17408 + wv * 13056;      // 3 chunks x 16 rows x 272 B
        const int hw0c = tail ? 4161 : hw0;       // tail window [4161..4224], in-bounds
        #pragma unroll
        for (int c = 0; c < 3; c++) {
            const int ob = (half * 3 + c) * 64 + wv * 16;
            const float* gb = t_out + (size_t)(b * 768 + ob) * 4225 + hw0c;
            #pragma unroll
            for (int r = 0; r < 16; r++) {
                __builtin_amdgcn_global_load_lds((guint*)(gb + (size_t)r * 4225 + l),
                                                 (luint*)(tw + c * 4352 + r * 272), 4, 0, 0);
            }
        }
        asm volatile("s_waitcnt vmcnt(0)" ::: "memory");

        // ---- 3 chunks: MFMA + exp epilogue, no memory stalls ----
        const float* tstf = (const float*)tw;
        float Zt[4], St[4], Dd[4], Zs[4];
        #pragma unroll
        for (int pt = 0; pt < 4; pt++) { Zt[pt] = 0.f; St[pt] = 0.f; Dd[pt] = 0.f; Zs[pt] = 0.f; }

        #pragma unroll
        for (int c = 0; c < 3; c++) {
            f32x4 acc[4];
            #pragma unroll
            for (int pt = 0; pt < 4; pt++) {
                f32x4 a0 = {0.f, 0.f, 0.f, 0.f};
                #pragma unroll
                for (int kf = 0; kf < 4; kf++)
                    a0 = __builtin_amdgcn_mfma_f32_16x16x32_bf16(afr[c][kf], bfrag[pt][kf], a0, 0, 0, 0);
                acc[pt] = a0;
            }
            #pragma unroll
            for (int pt = 0; pt < 4; pt++) {
                #pragma unroll
                for (int r = 0; r < 4; r++) {
                    float tv  = tstf[c * 1088 + (q * 4 + r) * 68 + (tail ? 63 : pt * 16 + n)];
                    float s1v = acc[pt][r] + bq[c][r];
                    float e   = __expf(tv);
                    Zt[pt] += e;
                    St[pt]  = fmaf(e, tv,  St[pt]);
                    Dd[pt]  = fmaf(e, s1v, Dd[pt]);
                    Zs[pt] += __expf(s1v);
                }
            }
        }

        // ---- merge 16 partitions per pixel, atomic per-pixel partials ----
        __syncthreads();
        {
            int part = wv * 4 + q;
            #pragma unroll
            for (int pt = 0; pt < 4; pt++) {
                f32x4 v = {Zt[pt], St[pt], Dd[pt], Zs[pt]};
                *(f32x4*)&scr[(pt * 16 + n) * 68 + part * 4] = v;
            }
        }
        __syncthreads();
        if (tid < 64) {
            float Z = 0.f, S = 0.f, D = 0.f, Z2 = 0.f;
            #pragma unroll
            for (int p = 0; p < 16; p++) {
                const float* s4 = &scr[tid * 68 + p * 4];
                Z += s4[0]; S += s4[1]; D += s4[2]; Z2 += s4[3];
            }
            float* dst = &ws[WS_PIX + ((size_t)b * 4288 + tile * 64 + tid) * 4];
            atomicAdd(dst + 0, Z);
            atomicAdd(dst + 1, S);
            atomicAdd(dst + 2, D);
            atomicAdd(dst + 3, Z2);
        }
    } else {
        // ---- rowstats role ----
        float* red = (float*)lds;
        int row  = bx - 2144;
        int side = (row >= 152) ? 1 : 0;
        int r    = side ? row - 152 : row;
        const float* src = side ? (t_logit + r * 4225) : (s_logit + r * 16641);

        float z = 0.f, s = 0.f;
        for (int k = tid; k < 16641; k += 256) {
            float v = side ? t_resized(src, k) : src[k];
            float e = __expf(v);
            z += e;
            s = fmaf(e, v, s);
        }
        for (int off = 32; off > 0; off >>= 1) { z += __shfl_down(z, off); s += __shfl_down(s, off); }
        if ((tid & 63) == 0) { red[tid >> 6] = z; red[4 + (tid >> 6)] = s; }
        __syncthreads();
        if (tid == 0) {
            float Z = red[0] + red[1] + red[2] + red[3];
            float S = red[4] + red[5] + red[6] + red[7];
            ws[WS_Z + row] = Z;
            atomicAdd(&ws[(side ? WS_E1 : WS_E0) + (r % 19)], S / Z - logf(Z));
        }
    }
}

// ---------------- mid: Gram (0..527) + pi finalize (528..661) ----------------
#define KT 512
#define KP 516
__global__ void k_mid(const float* __restrict__ s_logit, const float* __restrict__ t_logit,
                      float* __restrict__ ws, float* __restrict__ out) {
    __shared__ __align__(16) char lds[39296];
    const int tid = threadIdx.x;
    const int bx  = blockIdx.x;

    if (bx < 528) {
        float* pbuf  = (float*)lds;
        float* rowiz = (float*)(lds + 39216);
        int side = (bx >= 264) ? 1 : 0;
        int rm   = side ? bx - 264 : bx;
        int b = rm / 33, kt = rm - b * 33;
        int k0 = kt * KT;

        if (tid < 19) rowiz[tid] = 1.0f / ws[WS_Z + side * 152 + b * 19 + tid];
        __syncthreads();

        for (int i = 0; i < 19; i++) {
            const float* src = side ? (t_logit + (b * 19 + i) * 4225) : (s_logit + (b * 19 + i) * 16641);
            float iz = rowiz[i];
            for (int kl = tid; kl < KT; kl += 256) {
                int k = k0 + kl;
                float p = 0.f;
                if (k < 16641) {
                    float v = side ? t_resized(src, k) : src[k];
                    p = __expf(v) * iz;
                }
                pbuf[i * KP + kl] = p;
            }
        }
        __syncthreads();

        if (tid < 190) {
            int t = tid, i = 0;
            while (t >= 19 - i) { t -= 19 - i; i++; }
            int j = i + t;
            const float* pi_ = &pbuf[i * KP];
            const float* pj_ = &pbuf[j * KP];
            float g = 0.f;
            #pragma unroll 4
            for (int kl = 0; kl < KT; kl += 4) {
                float4 a = *(const float4*)&pi_[kl];
                float4 c = *(const float4*)&pj_[kl];
                g = fmaf(a.x, c.x, g); g = fmaf(a.y, c.y, g);
                g = fmaf(a.z, c.z, g); g = fmaf(a.w, c.w, g);
            }
            atomicAdd(&ws[(side ? WS_G1 : WS_G0) + i * 19 + j], g);
        }
    } else {
        // pi finalize: one thread per padded pixel
        float* red = (float*)lds;
        int gp = (bx - 528) * 256 + tid;      // 0..34303
        int b  = gp / 4288;
        int tp = gp - b * 4288;
        f32x4 a = *(const f32x4*)&ws[WS_PIX + (size_t)gp * 4];
        float Z = a[0], S = a[1], D = a[2], Z2 = a[3];
        float contrib = (tp < 4225) ? ((S - D) / Z - logf(Z) + logf(Z2)) : 0.f;
        for (int off = 32; off > 0; off >>= 1) contrib += __shfl_down(contrib, off);
        if ((tid & 63) == 0) red[tid >> 6] = contrib;
        __syncthreads();
        if (tid == 0)
            atomicAdd(out, (red[0] + red[1] + red[2] + red[3]) * (1.0f / 25958400.0f));
    }
}

// ---------------- finalize lo_loss (1 block, 384 threads) ----------------
__global__ void k_final(const float* __restrict__ ws, float* __restrict__ out) {
    __shared__ float Ms[361], Mt[361], ns[19], nt[19];
    __shared__ float red[8];
    int tid = threadIdx.x;
    if (tid < 361) {
        int i = tid / 19, j = tid - i * 19;
        int lo = min(i, j), hi = max(i, j);
        Ms[tid] = (ws[WS_E0 + hi] - ws[WS_G0 + lo * 19 + hi]) * 0.125f;
        Mt[tid] = (ws[WS_E1 + hi] - ws[WS_G1 + lo * 19 + hi]) * 0.125f;
    }
    __syncthreads();
    if (tid < 19) {
        float as = 0.f, at = 0.f;
        for (int j = 0; j < 19; j++) {
            as = fmaf(Ms[tid * 19 + j], Ms[tid * 19 + j], as);
            at = fmaf(Mt[tid * 19 + j], Mt[tid * 19 + j], at);
        }
        ns[tid] = fmaxf(sqrtf(as), 1e-12f);
        nt[tid] = fmaxf(sqrtf(at), 1e-12f);
    }
    __syncthreads();
    float d = 0.f;
    if (tid < 361) {
        int i = tid / 19;
        float v = Ms[tid] / ns[i] - Mt[tid] / nt[i];
        d = v * v;
    }
    for (int off = 32; off > 0; off >>= 1) d += __shfl_down(d, off);
    if ((tid & 63) == 0) red[tid >> 6] = d;
    __syncthreads();
    if (tid == 0) out[1] = red[0] + red[1] + red[2] + red[3] + red[4] + red[5];
}

extern "C" void kernel_launch(void* const* d_in, const int* in_sizes, int n_in,
                              void* d_out, int out_size, void* d_ws, size_t ws_size,
                              hipStream_t stream) {
    const float* s_out   = (const float*)d_in[0];
    const float* t_out   = (const float*)d_in[1];
    const float* t_logit = (const float*)d_in[2];
    const float* s_logit = (const float*)d_in[3];
    const float* conv_w  = (const float*)d_in[4];
    const float* conv_b  = (const float*)d_in[5];
    float* out = (float*)d_out;
    float* ws  = (float*)d_ws;

    k_init<<<dim3(536), dim3(256), 0, stream>>>(conv_w, ws, out);
    k_main<<<dim3(2448), dim3(256), 0, stream>>>(s_out, t_out, conv_b, s_logit, t_logit, ws, out);
    k_mid<<<dim3(662), dim3(256), 0, stream>>>(s_logit, t_logit, ws, out);
    k_final<<<dim3(1), dim3(384), 0, stream>>>(ws, out);
}

// Round 6
// 276.052 us; speedup vs baseline: 1.0887x; 1.0887x over previous
//
#include <hip/hip_runtime.h>
#include <math.h>

// ---------------- workspace layout (float offsets) ----------------
#define WS_E0   0       // E_s[19]
#define WS_E1   19      // E_t[19]
#define WS_G0   64      // G_s[361] (i<=j)
#define WS_G1   448     // G_t[361]
#define WS_Z    1152    // row sumexp [304]
#define WS_WBF  2048    // conv_w as bf16 [768*128] -> 49152 float slots
#define WS_PART 51200   // quarter partials [4][8][4224][4] f32 = 540672 floats
// total 591872 floats = 2.37 MB

typedef __bf16 bf16x8 __attribute__((ext_vector_type(8)));
typedef float  f32x4  __attribute__((ext_vector_type(4)));
typedef const __attribute__((address_space(1))) unsigned int guint;
typedef       __attribute__((address_space(3))) unsigned int luint;

// ---------------- init: zero accumulators + convert W to bf16 ----------------
__global__ void k_init(const float* __restrict__ conv_w, float* __restrict__ ws,
                       float* __restrict__ out) {
    const int bx = blockIdx.x, tid = threadIdx.x;
    if (bx < 96) {
        __bf16* Wb = (__bf16*)(ws + WS_WBF);
        #pragma unroll
        for (int j = 0; j < 4; j++) {
            int idx = bx * 1024 + j * 256 + tid;
            Wb[idx] = (__bf16)conv_w[idx];
        }
    } else {
        for (int k = tid; k < 2048; k += 256) ws[k] = 0.f;
        if (tid < 2) out[tid] = 0.f;
    }
}

// ---------------- bilinear sample of t_logit row (65x65 -> 129x129) ----------------
__device__ __forceinline__ float t_resized(const float* __restrict__ Trow, int k) {
    int y = k / 129, x = k - y * 129;
    int y0 = y >> 1, x0 = x >> 1;
    int y1 = y0 + (y & 1), x1 = x0 + (x & 1);
    float fy = 0.5f * (float)(y & 1), fx = 0.5f * (float)(x & 1);
    float v00 = Trow[y0 * 65 + x0], v01 = Trow[y0 * 65 + x1];
    float v10 = Trow[y1 * 65 + x0], v11 = Trow[y1 * 65 + x1];
    float r0 = v00 + fx * (v01 - v00);
    float r1 = v10 + fx * (v11 - v10);
    return r0 + fy * (r1 - r0);
}

// ---------------- main: rowstats (0..303) + pi (304..1359) + corner px (1360..1367) --
// pi block = (b, strip of 128 px, ch-quarter of 192). Per wave: 16 ch x 128 px.
// t_out streamed as 512-B contiguous row segments via double-buffered async
// global_load_lds (per-wave tiles, no barriers in loop, 8 KB in flight/wave).
__launch_bounds__(256, 2)
__global__ void k_main(const float* __restrict__ s_out, const float* __restrict__ t_out,
                       const float* __restrict__ conv_w, const float* __restrict__ bias,
                       const float* __restrict__ s_logit, const float* __restrict__ t_logit,
                       float* __restrict__ ws, float* __restrict__ out) {
    __shared__ __align__(16) char lds[67584];   // 2 bufs x 4 waves x 16 rows x 528 B
    const int tid = threadIdx.x;
    const int bx  = blockIdx.x;

    if (bx >= 304 && bx < 1360) {
        // ================= pi role =================
        const int idx     = bx - 304;
        const int quarter = idx & 3;
        const int bs      = idx >> 2;
        const int b       = bs / 33;
        const int strip   = bs - b * 33;
        const int px0     = strip * 128;          // px0+127 <= 4223, always in-bounds

        __bf16* xs = (__bf16*)lds;                // 128 px x 136 c bf16 (pre-loop only)

        // ---- bilinear resize 33x33 -> 65x65, 128-px strip, into xs[px][c] ----
        {
            const float* Sb = s_out + b * 128 * 1089;
            #pragma unroll
            for (int ii = 0; ii < 64; ii++) {
                int id2 = tid + ii * 256;
                int c = id2 >> 7, px = id2 & 127;
                int hw = px0 + px;
                int h = hw / 65, w = hw - h * 65;
                int y0 = h >> 1, x0 = w >> 1;
                int y1 = y0 + (h & 1), x1 = x0 + (w & 1);
                float wy = 0.5f * (float)(h & 1), wx = 0.5f * (float)(w & 1);
                const float* Sc = Sb + c * 1089;
                float v00 = Sc[y0 * 33 + x0], v01 = Sc[y0 * 33 + x1];
                float v10 = Sc[y1 * 33 + x0], v11 = Sc[y1 * 33 + x1];
                float r0 = v00 + wx * (v01 - v00);
                float r1 = v10 + wx * (v11 - v10);
                xs[px * 136 + c] = (__bf16)(r0 + wy * (r1 - r0));
            }
        }
        __syncthreads();

        const int l = tid & 63, g = tid >> 6, q = l >> 4, n = l & 15;

        // ---- B fragments: full K=128, all 8 px-groups, loaded once ----
        bf16x8 bfrag[8][4];
        #pragma unroll
        for (int pt = 0; pt < 8; pt++)
            #pragma unroll
            for (int kf = 0; kf < 4; kf++)
                bfrag[pt][kf] = *(const bf16x8*)&xs[(pt * 16 + n) * 136 + kf * 32 + q * 8];
        __syncthreads();   // xs dead; region becomes t double-buffers

        const __bf16* Wbf = (const __bf16*)(ws + WS_WBF);
        const int og = quarter * 192 + g * 16;   // wave's base channel (+c*64 per chunk)

        // async t fill: wave's 16 rows, 2x 256-B (4B/lane) per row, rows padded 528 B
        const float* gbl = t_out + ((size_t)(b * 768 + og)) * 4225 + px0 + l;
        char* lbw = lds + g * 8448;
        auto issue_t = [&](int cc, int sel) {
            const float* gb = gbl + (size_t)cc * 64 * 4225;
            char* lb = lbw + sel * 33792;
            #pragma unroll
            for (int r = 0; r < 16; r++) {
                __builtin_amdgcn_global_load_lds((guint*)(gb + (size_t)r * 4225),
                                                 (luint*)(lb + r * 528), 4, 0, 0);
                __builtin_amdgcn_global_load_lds((guint*)(gb + (size_t)r * 4225 + 64),
                                                 (luint*)(lb + r * 528 + 256), 4, 0, 0);
            }
        };
        auto load_a = [&](int cc, bf16x8* afr, f32x4& bqv) {
            const __bf16* Wr = Wbf + (size_t)(og + cc * 64 + n) * 128 + q * 8;
            #pragma unroll
            for (int kf = 0; kf < 4; kf++) afr[kf] = *(const bf16x8*)(Wr + kf * 32);
            bqv = *(const f32x4*)&bias[og + cc * 64 + q * 4];
        };

        bf16x8 afr[2][4];
        f32x4  bq[2];
        load_a(0, afr[0], bq[0]);
        issue_t(0, 0);

        float Zt[8], St[8], Dd[8], Zs[8];
        #pragma unroll
        for (int pt = 0; pt < 8; pt++) { Zt[pt] = 0.f; St[pt] = 0.f; Dd[pt] = 0.f; Zs[pt] = 0.f; }

        for (int c = 0; c < 3; c++) {
            const int cur = c & 1;
            asm volatile("s_waitcnt vmcnt(0)" ::: "memory");
            if (c < 2) { load_a(c + 1, afr[1 - cur], bq[1 - cur]); issue_t(c + 1, 1 - cur); }

            const float* tw = (const float*)(lbw + cur * 33792);
            #pragma unroll
            for (int pt = 0; pt < 8; pt++) {
                f32x4 a0 = {0.f, 0.f, 0.f, 0.f};
                #pragma unroll
                for (int kf = 0; kf < 4; kf++)
                    a0 = __builtin_amdgcn_mfma_f32_16x16x32_bf16(afr[cur][kf], bfrag[pt][kf], a0, 0, 0, 0);
                #pragma unroll
                for (int r = 0; r < 4; r++) {
                    float tv  = tw[(q * 4 + r) * 132 + pt * 16 + n];
                    float s1v = a0[r] + bq[cur][r];
                    float e   = __expf(tv);
                    Zt[pt] += e;
                    St[pt]  = fmaf(e, tv,  St[pt]);
                    Dd[pt]  = fmaf(e, s1v, Dd[pt]);
                    Zs[pt] += __expf(s1v);
                }
            }
        }

        // ---- merge 16 partitions (4 waves x 4 quads) per pixel ----
        __syncthreads();
        float* scr = (float*)lds;
        {
            int p = g * 4 + q;
            #pragma unroll
            for (int pt = 0; pt < 8; pt++) {
                f32x4 v = {Zt[pt], St[pt], Dd[pt], Zs[pt]};
                *(f32x4*)&scr[(pt * 16 + n) * 68 + p * 4] = v;
            }
        }
        __syncthreads();
        if (tid < 128) {
            float Z = 0.f, S = 0.f, D = 0.f, Z2 = 0.f;
            #pragma unroll
            for (int p = 0; p < 16; p++) {
                f32x4 v = *(const f32x4*)&scr[tid * 68 + p * 4];
                Z += v[0]; S += v[1]; D += v[2]; Z2 += v[3];
            }
            f32x4 o4 = {Z, S, D, Z2};
            *(f32x4*)&ws[WS_PART + (((size_t)quarter * 8 + b) * 4224 + px0 + tid) * 4] = o4;
        }
    } else if (bx < 304) {
        // ================= rowstats role =================
        float* red = (float*)lds;
        int row  = bx;
        int side = (row >= 152) ? 1 : 0;
        int r    = side ? row - 152 : row;
        const float* src = side ? (t_logit + r * 4225) : (s_logit + r * 16641);

        float z = 0.f, s = 0.f;
        for (int k = tid; k < 16641; k += 256) {
            float v = side ? t_resized(src, k) : src[k];
            float e = __expf(v);
            z += e;
            s = fmaf(e, v, s);
        }
        for (int off = 32; off > 0; off >>= 1) { z += __shfl_down(z, off); s += __shfl_down(s, off); }
        if ((tid & 63) == 0) { red[tid >> 6] = z; red[4 + (tid >> 6)] = s; }
        __syncthreads();
        if (tid == 0) {
            float Z = red[0] + red[1] + red[2] + red[3];
            float S = red[4] + red[5] + red[6] + red[7];
            ws[WS_Z + row] = Z;
            atomicAdd(&ws[(side ? WS_E1 : WS_E0) + (r % 19)], S / Z - logf(Z));
        }
    } else {
        // ================= corner pixel (px 4224) role, one block per b ==========
        // px 4224 = (h=64,w=64): resize is the exact corner sample s_out[...][32][32].
        float* xc  = (float*)lds;          // 128
        float* red = (float*)lds + 128;    // 16
        const int b = bx - 1360;
        if (tid < 128) xc[tid] = s_out[((size_t)b * 128 + tid) * 1089 + 1088];
        __syncthreads();
        float z = 0.f, s = 0.f, d = 0.f, z2 = 0.f;
        #pragma unroll
        for (int rep = 0; rep < 3; rep++) {
            int o = tid + rep * 256;
            const float* Wr = conv_w + (size_t)o * 128;
            float s1 = bias[o];
            for (int cc = 0; cc < 128; cc++) s1 = fmaf(Wr[cc], xc[cc], s1);
            float tv = t_out[((size_t)(b * 768 + o)) * 4225 + 4224];
            float e  = __expf(tv);
            z += e; s = fmaf(e, tv, s); d = fmaf(e, s1, d); z2 += __expf(s1);
        }
        for (int off = 32; off > 0; off >>= 1) {
            z += __shfl_down(z, off); s += __shfl_down(s, off);
            d += __shfl_down(d, off); z2 += __shfl_down(z2, off);
        }
        if ((tid & 63) == 0) {
            int wv = tid >> 6;
            red[wv] = z; red[4 + wv] = s; red[8 + wv] = d; red[12 + wv] = z2;
        }
        __syncthreads();
        if (tid == 0) {
            float Z = red[0] + red[1] + red[2] + red[3];
            float S = red[4] + red[5] + red[6] + red[7];
            float D = red[8] + red[9] + red[10] + red[11];
            float Z2 = red[12] + red[13] + red[14] + red[15];
            float contrib = (S - D) / Z - logf(Z) + logf(Z2);
            atomicAdd(out, contrib * (1.0f / 25958400.0f));
        }
    }
}

// ---------------- mid: Gram (0..527) + pi finalize (528..659) ----------------
#define KT 512
#define KP 516
__global__ void k_mid(const float* __restrict__ s_logit, const float* __restrict__ t_logit,
                      float* __restrict__ ws, float* __restrict__ out) {
    __shared__ __align__(16) char lds[39296];
    const int tid = threadIdx.x;
    const int bx  = blockIdx.x;

    if (bx < 528) {
        float* pbuf  = (float*)lds;
        float* rowiz = (float*)(lds + 39216);
        int side = (bx >= 264) ? 1 : 0;
        int rm   = side ? bx - 264 : bx;
        int b = rm / 33, kt = rm - b * 33;
        int k0 = kt * KT;

        if (tid < 19) rowiz[tid] = 1.0f / ws[WS_Z + side * 152 + b * 19 + tid];
        __syncthreads();

        for (int i = 0; i < 19; i++) {
            const float* src = side ? (t_logit + (b * 19 + i) * 4225) : (s_logit + (b * 19 + i) * 16641);
            float iz = rowiz[i];
            for (int kl = tid; kl < KT; kl += 256) {
                int k = k0 + kl;
                float p = 0.f;
                if (k < 16641) {
                    float v = side ? t_resized(src, k) : src[k];
                    p = __expf(v) * iz;
                }
                pbuf[i * KP + kl] = p;
            }
        }
        __syncthreads();

        if (tid < 190) {
            int t = tid, i = 0;
            while (t >= 19 - i) { t -= 19 - i; i++; }
            int j = i + t;
            const float* pi_ = &pbuf[i * KP];
            const float* pj_ = &pbuf[j * KP];
            float g = 0.f;
            #pragma unroll 4
            for (int kl = 0; kl < KT; kl += 4) {
                float4 a = *(const float4*)&pi_[kl];
                float4 c = *(const float4*)&pj_[kl];
                g = fmaf(a.x, c.x, g); g = fmaf(a.y, c.y, g);
                g = fmaf(a.z, c.z, g); g = fmaf(a.w, c.w, g);
            }
            atomicAdd(&ws[(side ? WS_G1 : WS_G0) + i * 19 + j], g);
        }
    } else {
        // pi finalize: 132 blocks x 256 threads = 33792 = 8 b x 4224 px
        float* red = (float*)lds;
        int gp = (bx - 528) * 256 + tid;
        int b  = gp / 4224;
        int tp = gp - b * 4224;
        float Z = 0.f, S = 0.f, D = 0.f, Z2 = 0.f;
        #pragma unroll
        for (int qq = 0; qq < 4; qq++) {
            f32x4 v = *(const f32x4*)&ws[WS_PART + (((size_t)qq * 8 + b) * 4224 + tp) * 4];
            Z += v[0]; S += v[1]; D += v[2]; Z2 += v[3];
        }
        float contrib = (S - D) / Z - logf(Z) + logf(Z2);
        for (int off = 32; off > 0; off >>= 1) contrib += __shfl_down(contrib, off);
        if ((tid & 63) == 0) red[tid >> 6] = contrib;
        __syncthreads();
        if (tid == 0)
            atomicAdd(out, (red[0] + red[1] + red[2] + red[3]) * (1.0f / 25958400.0f));
    }
}

// ---------------- finalize lo_loss (1 block, 384 threads) ----------------
__global__ void k_final(const float* __restrict__ ws, float* __restrict__ out) {
    __shared__ float Ms[361], Mt[361], ns[19], nt[19];
    __shared__ float red[8];
    int tid = threadIdx.x;
    if (tid < 361) {
        int i = tid / 19, j = tid - i * 19;
        int lo = min(i, j), hi = max(i, j);
        Ms[tid] = (ws[WS_E0 + hi] - ws[WS_G0 + lo * 19 + hi]) * 0.125f;
        Mt[tid] = (ws[WS_E1 + hi] - ws[WS_G1 + lo * 19 + hi]) * 0.125f;
    }
    __syncthreads();
    if (tid < 19) {
        float as = 0.f, at = 0.f;
        for (int j = 0; j < 19; j++) {
            as = fmaf(Ms[tid * 19 + j], Ms[tid * 19 + j], as);
            at = fmaf(Mt[tid * 19 + j], Mt[tid * 19 + j], at);
        }
        ns[tid] = fmaxf(sqrtf(as), 1e-12f);
        nt[tid] = fmaxf(sqrtf(at), 1e-12f);
    }
    __syncthreads();
    float d = 0.f;
    if (tid < 361) {
        int i = tid / 19;
        float v = Ms[tid] / ns[i] - Mt[tid] / nt[i];
        d = v * v;
    }
    for (int off = 32; off > 0; off >>= 1) d += __shfl_down(d, off);
    if ((tid & 63) == 0) red[tid >> 6] = d;
    __syncthreads();
    if (tid == 0) out[1] = red[0] + red[1] + red[2] + red[3] + red[4] + red[5];
}

extern "C" void kernel_launch(void* const* d_in, const int* in_sizes, int n_in,
                              void* d_out, int out_size, void* d_ws, size_t ws_size,
                              hipStream_t stream) {
    const float* s_out   = (const float*)d_in[0];
    const float* t_out   = (const float*)d_in[1];
    const float* t_logit = (const float*)d_in[2];
    const float* s_logit = (const float*)d_in[3];
    const float* conv_w  = (const float*)d_in[4];
    const float* conv_b  = (const float*)d_in[5];
    float* out = (float*)d_out;
    float* ws  = (float*)d_ws;

    k_init<<<dim3(97), dim3(256), 0, stream>>>(conv_w, ws, out);
    k_main<<<dim3(1368), dim3(256), 0, stream>>>(s_out, t_out, conv_w, conv_b,
                                                 s_logit, t_logit, ws, out);
    k_mid<<<dim3(660), dim3(256), 0, stream>>>(s_logit, t_logit, ws, out);
    k_final<<<dim3(1), dim3(384), 0, stream>>>(ws, out);
}